// Round 1
// baseline (599.490 us; speedup 1.0000x reference)
//
#include <hip/hip_runtime.h>
#include <stdint.h>

#define BATCH 8192
#define IN 4096
#define OUT 4096
#define EPS 1e-4f
#define KW 64              // u64 words per row (4096 bits)
#define RCHUNK 128         // rows per partial-sum block
#define NCHUNKS (BATCH / RCHUNK)   // 64

typedef unsigned long long u64;

// ---------------- Kernel 1: partial column sums (S1, S2) ----------------
__global__ __launch_bounds__(256) void colstat_partial(
    const float* __restrict__ x, float* __restrict__ P1, float* __restrict__ P2) {
    int col = blockIdx.x * 256 + threadIdx.x;
    int r0 = blockIdx.y * RCHUNK;
    float s1 = 0.f, s2 = 0.f;
    const float* p = x + (size_t)r0 * IN + col;
    for (int r = 0; r < RCHUNK; ++r) {
        float v = p[(size_t)r * IN];
        s1 += v;
        s2 += v * v;
    }
    P1[blockIdx.y * IN + col] = s1;
    P2[blockIdx.y * IN + col] = s2;
}

// ---------------- Kernel 2: finalize mu, a = rstd*gamma ----------------
__global__ __launch_bounds__(256) void colstat_final(
    const float* __restrict__ P1, const float* __restrict__ P2,
    const float* __restrict__ gamma, float* __restrict__ mu, float* __restrict__ aArr) {
    int col = blockIdx.x * 256 + threadIdx.x;
    double s1 = 0.0, s2 = 0.0;
    for (int c = 0; c < NCHUNKS; ++c) {
        s1 += (double)P1[c * IN + col];
        s2 += (double)P2[c * IN + col];
    }
    double m = s1 / (double)BATCH;
    double var = s2 / (double)BATCH - m * m;
    float rstd = (float)(1.0 / sqrt(var + (double)EPS));
    mu[col] = (float)m;
    aArr[col] = rstd * gamma[col];
}

// ---------------- Kernel 3: binarize + bit-pack x ----------------
__global__ __launch_bounds__(256) void binx(
    const float* __restrict__ x, const float* __restrict__ mu,
    const float* __restrict__ aArr, const float* __restrict__ beta,
    u64* __restrict__ xbits) {
    int r = blockIdx.x;
    int tid = threadIdx.x;
    int lane = tid & 63;
    int wv = tid >> 6;                // wave id, 0..3
    const float* row = x + (size_t)r * IN;
    for (int it = 0; it < IN / 256; ++it) {
        int col = it * 256 + tid;
        float v = row[col];
        float s = (v - mu[col]) * aArr[col] + beta[col];
        u64 mask = __ballot(s > 0.f);
        if (lane == 0) xbits[(size_t)r * KW + it * 4 + wv] = mask;
    }
}

// ---------------- Kernel 4: binarize weight rows + scale ----------------
__global__ __launch_bounds__(256) void binw(
    const float* __restrict__ w, u64* __restrict__ wbits, float* __restrict__ scale) {
    __shared__ double red[4];
    __shared__ double bcast;
    int o = blockIdx.x;
    int tid = threadIdx.x;
    int lane = tid & 63;
    int wv = tid >> 6;
    const float* row = w + (size_t)o * IN;

    // pass 1: row mean
    float part = 0.f;
    for (int it = 0; it < IN / 256; ++it) part += row[it * 256 + tid];
    double d = (double)part;
    for (int off = 32; off > 0; off >>= 1) d += __shfl_down(d, off, 64);
    if (lane == 0) red[wv] = d;
    __syncthreads();
    if (tid == 0) bcast = (red[0] + red[1] + red[2] + red[3]) / (double)IN;
    __syncthreads();
    float mean = (float)bcast;

    // pass 2: sign bits + L1 scale of clipped centered weights
    float absacc = 0.f;
    for (int it = 0; it < IN / 256; ++it) {
        float wc = row[it * 256 + tid] - mean;
        u64 mask = __ballot(wc > 0.f);
        if (lane == 0) wbits[(size_t)o * KW + it * 4 + wv] = mask;
        absacc += fminf(fabsf(wc), 1.0f);
    }
    double da = (double)absacc;
    for (int off = 32; off > 0; off >>= 1) da += __shfl_down(da, off, 64);
    if (lane == 0) red[wv] = da;
    __syncthreads();
    if (tid == 0) bcast = (red[0] + red[1] + red[2] + red[3]) / (double)IN;
    __syncthreads();
    if (tid == 0) scale[o] = (float)bcast;
}

// ---------------- Kernel 5: binary GEMM (xnor-popcount) ----------------
// 128x128 tile per block, 256 threads, 8x8 micro-tile (interleaved by 16)
#define BK 16              // u64 words per K-chunk (1024 bits)
#define LSTR 17            // padded LDS stride in u64
__global__ __launch_bounds__(256, 2) void bgemm(
    const u64* __restrict__ xbits, const u64* __restrict__ wbits,
    const float* __restrict__ scale, const float* __restrict__ bias,
    float* __restrict__ out) {
    __shared__ u64 xs[128 * LSTR];
    __shared__ u64 wsm[128 * LSTR];

    int tid = threadIdx.x;
    int tx = tid & 15;
    int ty = tid >> 4;
    int colBase = blockIdx.x * 128;
    int rowBase = blockIdx.y * 128;

    int acc[8][8];
#pragma unroll
    for (int i = 0; i < 8; ++i)
#pragma unroll
        for (int j = 0; j < 8; ++j) acc[i][j] = 0;

    for (int kc = 0; kc < KW / BK; ++kc) {
        // stage tiles
        const u64* xg = xbits + (size_t)rowBase * KW + kc * BK;
        const u64* wg = wbits + (size_t)colBase * KW + kc * BK;
#pragma unroll
        for (int li = 0; li < 128 * BK / 256; ++li) {
            int idx = tid + li * 256;
            int r = idx >> 4, wd = idx & 15;
            xs[r * LSTR + wd] = xg[(size_t)r * KW + wd];
            wsm[r * LSTR + wd] = wg[(size_t)r * KW + wd];
        }
        __syncthreads();

#pragma unroll 4
        for (int k = 0; k < BK; ++k) {
            u64 xv[8], wvv[8];
#pragma unroll
            for (int i = 0; i < 8; ++i) xv[i] = xs[(ty + 16 * i) * LSTR + k];
#pragma unroll
            for (int j = 0; j < 8; ++j) wvv[j] = wsm[(tx + 16 * j) * LSTR + k];
#pragma unroll
            for (int i = 0; i < 8; ++i)
#pragma unroll
                for (int j = 0; j < 8; ++j)
                    acc[i][j] += (int)__popcll(xv[i] ^ wvv[j]);
        }
        __syncthreads();
    }

    // epilogue: dot = IN - 2*mismatches; y = relu((dot + bias) * scale)
    float sc[8], bs[8];
#pragma unroll
    for (int j = 0; j < 8; ++j) {
        int c = colBase + tx + 16 * j;
        sc[j] = scale[c];
        bs[j] = bias[c];
    }
#pragma unroll
    for (int i = 0; i < 8; ++i) {
        int r = rowBase + ty + 16 * i;
        float* orow = out + (size_t)r * OUT;
#pragma unroll
        for (int j = 0; j < 8; ++j) {
            int c = colBase + tx + 16 * j;
            float dot = (float)(IN - 2 * acc[i][j]);
            float y = (dot + bs[j]) * sc[j];
            orow[c] = y > 0.f ? y : 0.f;
        }
    }
}

extern "C" void kernel_launch(void* const* d_in, const int* in_sizes, int n_in,
                              void* d_out, int out_size, void* d_ws, size_t ws_size,
                              hipStream_t stream) {
    const float* x = (const float*)d_in[0];
    const float* gamma = (const float*)d_in[1];
    const float* beta = (const float*)d_in[2];
    const float* weight = (const float*)d_in[3];
    const float* bias = (const float*)d_in[4];
    float* out = (float*)d_out;

    char* w = (char*)d_ws;
    float* mu = (float*)(w);                       // 16KB
    float* aArr = (float*)(w + (1 << 14));         // 16KB
    float* scale = (float*)(w + (2 << 14));        // 16KB
    float* P1 = (float*)(w + (1 << 16));           // 1MB
    float* P2 = (float*)(w + (1 << 16) + (1 << 20));
    u64* xbits = (u64*)(w + (1 << 16) + (2 << 20));       // 4MB
    u64* wbits = xbits + (size_t)BATCH * KW;              // 2MB

    colstat_partial<<<dim3(IN / 256, NCHUNKS), 256, 0, stream>>>(x, P1, P2);
    colstat_final<<<dim3(IN / 256), 256, 0, stream>>>(P1, P2, gamma, mu, aArr);
    binx<<<dim3(BATCH), 256, 0, stream>>>(x, mu, aArr, beta, xbits);
    binw<<<dim3(OUT), 256, 0, stream>>>(weight, wbits, scale);
    bgemm<<<dim3(OUT / 128, BATCH / 128), 256, 0, stream>>>(xbits, wbits, scale, bias, out);
}